// Round 5
// baseline (88.331 us; speedup 1.0000x reference)
//
#include <hip/hip_runtime.h>
#include <math.h>

// TopologicalValuePolicy — MI355X, R5 (= R4 with sliding-window off-by-one fixed).
// conv[p][v] = 6*(Wv - Cv) - 5*(W0+W1+W2) over 5-windows along 4 line
// orientations. With e0 = l0-5(l1+l2), e1 = l1-5(l0+l2):
//   a_v = (5-sum of e_v along oriented line) - 6*C_v
// 320-thread blocks (one position/thread, no wave-0 tail); precompute sliding
// loops unrolled to fixed 21 trips. Window i covers cells i..i+4; transition
// i -> i+1 is +cell(i+5) - cell(i)  [R4 bug: used (i+6)/(i+1)].
// Out-of-range unrolled reads (i >= cnt) land at index <= base+25*step, all
// inside the E/C regions written before the barrier — race-free; writes for
// invalid i are steered to a DUMMY slot.

__device__ __forceinline__ float fpow(float x, float e) {
    float r = __builtin_amdgcn_exp2f(e * __builtin_amdgcn_logf(x));
    return (x > 0.f) ? r : 0.f;
}
__device__ __forceinline__ float fexp(float x) {
    return __builtin_amdgcn_exp2f(x * 1.44269504088896f);
}

#define OFF_E0 0        // e0 plane, 27x27 zero-padded
#define OFF_E1 729      // e1 plane
#define OFF_C0 1458     // 6*l0 centers, 17x17
#define OFF_C1 1747
#define OFF_GH 2036     // horizontal 5-sums: [f:357][line(17):21][k(21)]
#define OFF_GV 2750     // vertical
#define OFF_GD 3464     // diagonal:      [f:726][line(33):22][k]
#define OFF_GA 4916     // anti-diagonal: [f:693][line(33):21][k]
#define DUMMY  6302     // write sink for invalid unrolled iterations
#define LDS_FLOATS 6303

__global__ __launch_bounds__(320) void topo_policy_value(
    const float* __restrict__ state,
    float* __restrict__ probs,
    float* __restrict__ value)
{
    __shared__ float lds[LDS_FLOATS];
    __shared__ float red[16];

    const int tid = threadIdx.x;
    const int b = blockIdx.x;

    // zero e0/e1 padded planes (1458 floats)
    #pragma unroll
    for (int i = 0; i < 5; ++i) {
        int idx = tid + i * 320;
        if (idx < 1458) lds[idx] = 0.0f;
    }
    __syncthreads();

    // stage: per board cell compute e0,e1 + pre-scaled centers
    const float* src = state + (size_t)b * (19 * 19 * 3);
    for (int j = tid; j < 361; j += 320) {
        int br = j / 19, bc = j - br * 19;
        float l0 = src[3 * j], l1 = src[3 * j + 1], l2 = src[3 * j + 2];
        float e0 = fmaf(-5.f, l1 + l2, l0);
        float e1 = fmaf(-5.f, l0 + l2, l1);
        int pi = (br + 4) * 27 + (bc + 4);
        lds[OFF_E0 + pi] = e0;
        lds[OFF_E1 + pi] = e1;
        if (br >= 1 && br <= 17 && bc >= 1 && bc <= 17) {
            int ci = (br - 1) * 17 + (bc - 1);
            lds[OFF_C0 + ci] = 6.f * l0;
            lds[OFF_C1 + ci] = 6.f * l1;
        }
    }
    __syncthreads();

    // oriented sliding 5-sums: 200 workers, fixed 21-trip unrolled loops
    if (tid < 200) {
        int t = tid, f, L;
        int base, step, outp, cnt;
        if (t < 34) {                       // horizontal
            f = t & 1; L = t >> 1;
            base = (L + 5) * 27 + 1; step = 1;
            outp = OFF_GH + f * 357 + L * 21; cnt = 21;
        } else if (t < 68) {                // vertical
            t -= 34; f = t & 1; L = t >> 1;
            base = 27 + (L + 5); step = 27;
            outp = OFF_GV + f * 357 + L * 21; cnt = 21;
        } else if (t < 134) {               // diagonal, delta = L-16
            t -= 68; f = t & 1; L = t >> 1;
            int d = L - 16;
            int j0 = (d < 0) ? -d : 0;
            base = (j0 + 1 + d) * 27 + (j0 + 1); step = 28;
            outp = OFF_GD + f * 726 + L * 22 + j0;
            cnt = 21 - ((d < 0) ? -d : d);
        } else {                            // anti-diagonal, sigma = L
            t -= 134; f = t & 1; L = t >> 1;
            int k0 = (L > 16) ? (L - 16) : 0;
            int k1 = (L + 4 < 20) ? (L + 4) : 20;
            base = 26 * k0 + 36 + L; step = 26;
            outp = OFF_GA + f * 693 + L * 21 + k0;
            cnt = k1 - k0 + 1;
        }
        const float* ef = lds + (f ? OFF_E1 : OFF_E0);
        float s = ef[base] + ef[base + step] + ef[base + 2 * step]
                + ef[base + 3 * step] + ef[base + 4 * step];
        #pragma unroll
        for (int i = 0; i < 21; ++i) {
            int dst = (i < cnt) ? (outp + i) : DUMMY;
            lds[dst] = s;
            s += ef[base + (i + 5) * step] - ef[base + i * step];
        }
    }
    __syncthreads();

    // main compute: one position per thread (289 of 320 active)
    const bool act = tid < 289;
    float fcur = 0.f, foth = 0.f;
    if (act) {
        const int y = tid / 17;
        const int x = tid - y * 17;
        const float h0 = lds[OFF_C0 + tid];
        const float h1 = lds[OFF_C1 + tid];

        const int bh = OFF_GH + y * 21 + x;
        const int bv = OFF_GV + x * 21 + y;
        const int bd = OFF_GD + (y - x + 16) * 22 + x;
        const int ba = OFF_GA + (y + x) * 21 + y;

        float sd0 = 0.f, sd1 = 0.f;
        #define ORIENT(B, FS)                                         \
        {                                                             \
            float t0 = 0.f, t1 = 0.f;                                 \
            _Pragma("unroll")                                         \
            for (int i = 0; i < 5; ++i) {                             \
                float a0 = lds[(B) + i] - h0;                         \
                float a1 = lds[(B) + (FS) + i] - h1;                  \
                a0 = fmaxf(a0, 0.f); a1 = fmaxf(a1, 0.f);             \
                float q0 = a0 * a0, q1 = a1 * a1;                     \
                float m0 = q0 * q0, m1 = q1 * q1;                     \
                t0 = fmaf(m0, q0, t0); t1 = fmaf(m1, q1, t1);         \
            }                                                         \
            sd0 += fpow(t0, 5.0f / 6.0f);                             \
            sd1 += fpow(t1, 5.0f / 6.0f);                             \
        }
        ORIENT(bh, 357)
        ORIENT(bv, 357)
        ORIENT(bd, 726)
        ORIENT(ba, 693)
        #undef ORIENT

        fcur = fpow(sd0, 0.2f);
        foth = fpow(sd1, 0.2f);
    }

    const float g = act ? 2.f * (fcur + foth) : -3.0e38f;
    float lmax = g;
    float ldif = fcur - foth;   // 0 when inactive

    #pragma unroll
    for (int off = 32; off > 0; off >>= 1) {
        lmax = fmaxf(lmax, __shfl_down(lmax, off, 64));
        ldif += __shfl_down(ldif, off, 64);
    }
    const int wave = tid >> 6;   // 0..4
    if ((tid & 63) == 0) { red[wave] = lmax; red[5 + wave] = ldif; }
    __syncthreads();
    if (tid == 0) {
        float m = red[0];
        #pragma unroll
        for (int w = 1; w < 5; ++w) m = fmaxf(m, red[w]);
        red[15] = m;
        red[14] = red[5] + red[6] + red[7] + red[8] + red[9];
    }
    __syncthreads();

    const float M = red[15];
    const float e = act ? fexp(g - M) : 0.f;
    float lsum = e;
    #pragma unroll
    for (int off = 32; off > 0; off >>= 1) lsum += __shfl_down(lsum, off, 64);
    if ((tid & 63) == 0) red[wave] = lsum;
    __syncthreads();
    if (tid == 0) red[13] = red[0] + red[1] + red[2] + red[3] + red[4];
    __syncthreads();

    const float invS = 1.0f / red[13];
    if (act) probs[(size_t)b * 289 + tid] = e * invS;
    if (tid == 0) value[b] = tanhf(red[14] * (0.2f / 32.0f));
}

extern "C" void kernel_launch(void* const* d_in, const int* in_sizes, int n_in,
                              void* d_out, int out_size, void* d_ws, size_t ws_size,
                              hipStream_t stream) {
    const float* state = (const float*)d_in[0];
    const int nb = in_sizes[0] / (19 * 19 * 3);   // 4096
    float* probs = (float*)d_out;                  // (nb, 289)
    float* value = probs + (size_t)nb * 289;       // (nb,)
    topo_policy_value<<<dim3(nb), dim3(320), 0, stream>>>(state, probs, value);
}

// Round 7
// 85.265 us; speedup vs baseline: 1.0360x; 1.0360x over previous
//
#include <hip/hip_runtime.h>
#include <math.h>

// TopologicalValuePolicy — MI355X, R6 (resubmit after GPU-broker timeout):
// field-interleaved float2 LDS.
// conv[p][v] = 6*(Wv - Cv) - 5*(W0+W1+W2) over 5-windows along 4 line
// orientations. With e0 = l0-5(l1+l2), e1 = l1-5(l0+l2):
//   a_v = (5-sum of e_v along oriented line) - 6*C_v
// Both fields (cur/oth) are always read at the same index -> store E, C and
// all G arrays as float2 (x=field0, y=field1). Halves LDS instruction count
// and address math; .x/.y pairs SLP-pack into v_pk_*_f32.
// Precompute: 100 workers (one per orientation-line, both fields), fixed
// 21-trip unrolled sliding window with register rolling buffer. Out-of-range
// unrolled reads stay inside the LDS allocation (max f2 index ~1176 < 3152)
// and may race concurrent G writes — value discarded, dword-atomic, safe.
// Writes for invalid trips steered to DUMMY.

__device__ __forceinline__ float fpow(float x, float e) {
    float r = __builtin_amdgcn_exp2f(e * __builtin_amdgcn_logf(x));
    return (x > 0.f) ? r : 0.f;
}
__device__ __forceinline__ float fexp(float x) {
    return __builtin_amdgcn_exp2f(x * 1.44269504088896f);
}

// float2-unit offsets
#define F2_E   0        // 27x27 zero-padded e-field pairs
#define F2_C   729      // 289 center pairs (6*l0, 6*l1)
#define F2_GH  1018     // [17][21]
#define F2_GV  1375     // [17][21]
#define F2_GD  1732     // [33][22]
#define F2_GA  2458     // [33][21]
#define F2_DUMMY 3151
#define F2_TOTAL 3152   // 25216 B -> 6 blocks/CU

__global__ __launch_bounds__(320) void topo_policy_value(
    const float* __restrict__ state,
    float* __restrict__ probs,
    float* __restrict__ value)
{
    __shared__ float2 l2[F2_TOTAL];
    __shared__ float red[16];

    const int tid = threadIdx.x;
    const int b = blockIdx.x;

    // zero E plane (729 float2)
    #pragma unroll
    for (int i = 0; i < 3; ++i) {
        int idx = tid + i * 320;
        if (idx < 729) l2[idx] = make_float2(0.f, 0.f);
    }
    __syncthreads();

    // stage: per board cell compute e-pair + center pair
    const float* src = state + (size_t)b * (19 * 19 * 3);
    for (int j = tid; j < 361; j += 320) {
        int br = j / 19, bc = j - br * 19;
        float l0 = src[3 * j], l1 = src[3 * j + 1], l2v = src[3 * j + 2];
        float e0 = fmaf(-5.f, l1 + l2v, l0);
        float e1 = fmaf(-5.f, l0 + l2v, l1);
        l2[F2_E + (br + 4) * 27 + (bc + 4)] = make_float2(e0, e1);
        if (br >= 1 && br <= 17 && bc >= 1 && bc <= 17) {
            l2[F2_C + (br - 1) * 17 + (bc - 1)] = make_float2(6.f * l0, 6.f * l1);
        }
    }
    __syncthreads();

    // oriented sliding 5-sums: 100 workers, both fields per thread
    if (tid < 100) {
        int t = tid, L;
        int base, step, outp, cnt;
        if (t < 17) {                       // horizontal
            L = t;
            base = (L + 5) * 27 + 1; step = 1;
            outp = F2_GH + L * 21; cnt = 21;
        } else if (t < 34) {                // vertical
            L = t - 17;
            base = 27 + (L + 5); step = 27;
            outp = F2_GV + L * 21; cnt = 21;
        } else if (t < 67) {                // diagonal, delta = L-16
            L = t - 34;
            int d = L - 16;
            int j0 = (d < 0) ? -d : 0;
            base = (j0 + 1 + d) * 27 + (j0 + 1); step = 28;
            outp = F2_GD + L * 22 + j0;
            cnt = 21 - ((d < 0) ? -d : d);
        } else {                            // anti-diagonal, sigma = L
            L = t - 67;
            int k0 = (L > 16) ? (L - 16) : 0;
            int k1 = (L + 4 < 20) ? (L + 4) : 20;
            base = 26 * k0 + 36 + L; step = 26;
            outp = F2_GA + L * 21 + k0;
            cnt = k1 - k0 + 1;
        }
        float2 buf[5];
        #pragma unroll
        for (int i = 0; i < 5; ++i) buf[i] = l2[base + i * step];
        float sx = buf[0].x + buf[1].x + buf[2].x + buf[3].x + buf[4].x;
        float sy = buf[0].y + buf[1].y + buf[2].y + buf[3].y + buf[4].y;
        #pragma unroll
        for (int i = 0; i < 21; ++i) {
            int dst = (i < cnt) ? (outp + i) : F2_DUMMY;
            l2[dst] = make_float2(sx, sy);
            float2 nc = l2[base + (i + 5) * step];   // window i -> i+1: +cell(i+5) -cell(i)
            float2 oc = buf[i % 5];
            sx += nc.x - oc.x;
            sy += nc.y - oc.y;
            buf[i % 5] = nc;
        }
    }
    __syncthreads();

    // main compute: one position per thread (289 of 320 active)
    const bool act = tid < 289;
    float fcur = 0.f, foth = 0.f;
    if (act) {
        const int y = tid / 17;
        const int x = tid - y * 17;
        const float2 h = l2[F2_C + tid];

        const int bh = F2_GH + y * 21 + x;
        const int bv = F2_GV + x * 21 + y;
        const int bd = F2_GD + (y - x + 16) * 22 + x;
        const int ba = F2_GA + (y + x) * 21 + y;

        float sd0 = 0.f, sd1 = 0.f;
        #define ORIENT(B)                                             \
        {                                                             \
            float t0 = 0.f, t1 = 0.f;                                 \
            _Pragma("unroll")                                         \
            for (int i = 0; i < 5; ++i) {                             \
                float2 w = l2[(B) + i];                               \
                float a0 = fmaxf(w.x - h.x, 0.f);                     \
                float a1 = fmaxf(w.y - h.y, 0.f);                     \
                float q0 = a0 * a0, q1 = a1 * a1;                     \
                float m0 = q0 * q0, m1 = q1 * q1;                     \
                t0 = fmaf(m0, q0, t0); t1 = fmaf(m1, q1, t1);         \
            }                                                         \
            sd0 += fpow(t0, 5.0f / 6.0f);                             \
            sd1 += fpow(t1, 5.0f / 6.0f);                             \
        }
        ORIENT(bh)
        ORIENT(bv)
        ORIENT(bd)
        ORIENT(ba)
        #undef ORIENT

        fcur = fpow(sd0, 0.2f);
        foth = fpow(sd1, 0.2f);
    }

    const float g = act ? 2.f * (fcur + foth) : -3.0e38f;
    float lmax = g;
    float ldif = fcur - foth;   // 0 when inactive

    #pragma unroll
    for (int off = 32; off > 0; off >>= 1) {
        lmax = fmaxf(lmax, __shfl_down(lmax, off, 64));
        ldif += __shfl_down(ldif, off, 64);
    }
    const int wave = tid >> 6;   // 0..4
    if ((tid & 63) == 0) { red[wave] = lmax; red[5 + wave] = ldif; }
    __syncthreads();
    if (tid == 0) {
        float m = red[0];
        #pragma unroll
        for (int w = 1; w < 5; ++w) m = fmaxf(m, red[w]);
        red[15] = m;
        red[14] = red[5] + red[6] + red[7] + red[8] + red[9];
    }
    __syncthreads();

    const float M = red[15];
    const float e = act ? fexp(g - M) : 0.f;
    float lsum = e;
    #pragma unroll
    for (int off = 32; off > 0; off >>= 1) lsum += __shfl_down(lsum, off, 64);
    if ((tid & 63) == 0) red[wave] = lsum;
    __syncthreads();
    if (tid == 0) red[13] = red[0] + red[1] + red[2] + red[3] + red[4];
    __syncthreads();

    const float invS = 1.0f / red[13];
    if (act) probs[(size_t)b * 289 + tid] = e * invS;
    if (tid == 0) value[b] = tanhf(red[14] * (0.2f / 32.0f));
}

extern "C" void kernel_launch(void* const* d_in, const int* in_sizes, int n_in,
                              void* d_out, int out_size, void* d_ws, size_t ws_size,
                              hipStream_t stream) {
    const float* state = (const float*)d_in[0];
    const int nb = in_sizes[0] / (19 * 19 * 3);   // 4096
    float* probs = (float*)d_out;                  // (nb, 289)
    float* value = probs + (size_t)nb * 289;       // (nb,)
    topo_policy_value<<<dim3(nb), dim3(320), 0, stream>>>(state, probs, value);
}